// Round 10
// baseline (327.803 us; speedup 1.0000x reference)
//
#include <hip/hip_runtime.h>

#define N_ROWS 1024
#define M_COLS 16384
#define DIM 512

constexpr float GAMMA_ = 0.1f;
constexpr float INV_GAMMA = 10.0f;
constexpr float EPS_ = 0.005f;
constexpr float TINY_ = 1e-30f;
constexpr float RVAL = 1.0f / 1024.0f;
constexpr float CVAL = 1.0f / 16384.0f;

typedef __attribute__((ext_vector_type(8))) short bf16x8;
typedef __attribute__((ext_vector_type(4))) float f32x4;
typedef unsigned long long u64;

__device__ __forceinline__ float waveRedSum(float v) {
#pragma unroll
    for (int o = 32; o > 0; o >>= 1) v += __shfl_down(v, o);
    return v;
}

// ---- L2-bypassing (coherent-point) accesses: relaxed system-scope atomics ----
__device__ __forceinline__ unsigned sysloadu(const unsigned* p) {
    return __hip_atomic_load(p, __ATOMIC_RELAXED, __HIP_MEMORY_SCOPE_SYSTEM);
}
__device__ __forceinline__ void sysstoreu(unsigned* p, unsigned v) {
    __hip_atomic_store(p, v, __ATOMIC_RELAXED, __HIP_MEMORY_SCOPE_SYSTEM);
}
__device__ __forceinline__ float sysloadf(const float* p) {
    return __hip_atomic_load(p, __ATOMIC_RELAXED, __HIP_MEMORY_SCOPE_SYSTEM);
}
__device__ __forceinline__ void sysstoref(float* p, float v) {
    __hip_atomic_store(p, v, __ATOMIC_RELAXED, __HIP_MEMORY_SCOPE_SYSTEM);
}
__device__ __forceinline__ u64 sysloadu64(const u64* p) {
    return __hip_atomic_load(p, __ATOMIC_RELAXED, __HIP_MEMORY_SCOPE_SYSTEM);
}
__device__ __forceinline__ void sysstoreu64(u64* p, u64 v) {
    __hip_atomic_store(p, v, __ATOMIC_RELAXED, __HIP_MEMORY_SCOPE_SYSTEM);
}

// ---- bf16 split helper (RNE) ----
__device__ __forceinline__ unsigned bf16b(float f) {
    unsigned u = __float_as_uint(f);
    return (u + 0x7FFFu + ((u >> 16) & 1u)) >> 16;
}

// ---- conv_x: f32 -> bf16 hi/lo (linear layout) + row sqnorm. 1024 blk x 64 thr ----
__global__ void conv_x(const float* __restrict__ X, unsigned short* __restrict__ xh,
                       unsigned short* __restrict__ xl, float* __restrict__ sx) {
    const int row = blockIdx.x, t = threadIdx.x;
    const float* xr = X + (size_t)row * DIM + t * 8;
    float4 a = *(const float4*)xr, c = *(const float4*)(xr + 4);
    float v[8] = {a.x, a.y, a.z, a.w, c.x, c.y, c.z, c.w};
    unsigned hs[8], ls[8];
    float sq = 0.f;
#pragma unroll
    for (int j = 0; j < 8; ++j) {
        unsigned h = bf16b(v[j]);
        hs[j] = h;
        ls[j] = bf16b(v[j] - __uint_as_float(h << 16));
        sq = fmaf(v[j], v[j], sq);
    }
    uint4 hv = make_uint4(hs[0] | (hs[1] << 16), hs[2] | (hs[3] << 16),
                          hs[4] | (hs[5] << 16), hs[6] | (hs[7] << 16));
    uint4 lv = make_uint4(ls[0] | (ls[1] << 16), ls[2] | (ls[3] << 16),
                          ls[4] | (ls[5] << 16), ls[6] | (ls[7] << 16));
    const size_t off = (size_t)row * 1024 + t * 16;   // bytes
    *(uint4*)((char*)xh + off) = hv;
    *(uint4*)((char*)xl + off) = lv;
    sq = waveRedSum(sq);
    if (t == 0) sx[row] = sq;
}

// ---- per-launch state init (graph replays do NOT re-poison ws/out; tags
// are epoch-compared so they MUST be zeroed every launch) ----
__global__ void init_state(unsigned* __restrict__ arr, u64* __restrict__ utag,
                           u64* __restrict__ mmintag, u64* __restrict__ errtot,
                           float* __restrict__ out) {
    int idx = blockIdx.x * blockDim.x + threadIdx.x;
    if (idx < 256) arr[idx] = 0u;
    if (idx < 2048) utag[idx] = 0ull;
    if (idx < 1024) mmintag[idx] = 0ull;
    if (idx < 4) errtot[idx] = 0ull;
    if (idx == 0) out[0] = 0.0f;
}

// ---- FUSED: y-staging + split-bf16 MFMA gemm (K in C-fragments) + leader
// row-min exchange + K=exp + Sinkhorn (ONE tagged leader exchange/iter) +
// P/loss epilogue.  256 blocks x 1024 thr. Block b owns cols [64b,64b+64),
// wave w rows [64w,64w+64). kf[i][j][reg]: row = 64w+16i+4q+reg (q=lane>>4),
// col(local) = 16j+l15.
// spart2: [row][writer] in dead P region; publish = 1 scattered sc-store/thread.
// Leaders b<16 own rows [64b,64b+64) (wave w: rows 64b+4w+q), publish u as
// (epoch<<32 | f32bits) 64-bit tagged stores; consumers poll the tags.
__global__ __launch_bounds__(1024) void sinkhorn_full(
        const unsigned short* __restrict__ xh, const unsigned short* __restrict__ xl,
        const float* __restrict__ Y, const float* __restrict__ sx,
        float* __restrict__ out, unsigned* __restrict__ arr,
        u64* __restrict__ utag, u64* __restrict__ mmintag,
        u64* __restrict__ errtot, float* __restrict__ err_p) {
    const int tid = threadIdx.x;
    const int b = blockIdx.x;
    const int lane = tid & 63;
    const int w = tid >> 6;
    const int l15 = lane & 15;
    const int q = lane >> 4;
    float* Pbuf = out + 1;
    float* spart2 = out + 10000000;          // [1024 rows][256 writers] f32 (dead P region)

    __shared__ __align__(16) char ldsY[131072];   // hi 64KB | lo 64KB, swizzled
    __shared__ float sx_lds[1024];
    __shared__ float mmin_lds[1024];
    __shared__ float u_lds[1024];
    __shared__ float u_prev_lds[1024];
    __shared__ float sy_lds[64];
    __shared__ float v_lds[2][64];
    __shared__ float t_acc[16][68];
    __shared__ float srow_lds[16][64];
    __shared__ float red[16];
    __shared__ float sh_err;
    __shared__ float sh_eprev;

    float u_prev = 1.0f;    // leader-only: this thread's owned row's u (l15==0 lanes)

    // ---- stage y tile: f32 -> split bf16 -> swizzled LDS; sy partials ----
    {
        const int row = tid >> 4;       // 0..63 (block's local col index)
        const int c = tid & 15;         // 32-f32 chunk within the row
        const float* yr = Y + (size_t)((b << 6) + row) * DIM + c * 32;
        const int swz = (row & 7) << 4;
        float sq = 0.f;
#pragma unroll
        for (int s2 = 0; s2 < 4; ++s2) {
            float4 f0 = *(const float4*)(yr + s2 * 8);
            float4 f1 = *(const float4*)(yr + s2 * 8 + 4);
            float v8[8] = {f0.x, f0.y, f0.z, f0.w, f1.x, f1.y, f1.z, f1.w};
            unsigned h[8], lo[8];
#pragma unroll
            for (int j = 0; j < 8; ++j) {
                h[j] = bf16b(v8[j]);
                lo[j] = bf16b(v8[j] - __uint_as_float(h[j] << 16));
                sq = fmaf(v8[j], v8[j], sq);
            }
            const int off = (row * 1024 + c * 64 + s2 * 16) ^ swz;
            *(uint4*)(ldsY + off) = make_uint4(h[0] | (h[1] << 16), h[2] | (h[3] << 16),
                                               h[4] | (h[5] << 16), h[6] | (h[7] << 16));
            *(uint4*)(ldsY + 65536 + off) = make_uint4(lo[0] | (lo[1] << 16), lo[2] | (lo[3] << 16),
                                                       lo[4] | (lo[5] << 16), lo[6] | (lo[7] << 16));
        }
        float* sy_part = (float*)t_acc;     // [64][17] fits t_acc
        sy_part[row * 17 + c] = sq;
        sx_lds[tid] = sx[tid];
        if (tid < 64) { v_lds[0][tid] = 1.0f; v_lds[1][tid] = 1.0f; }
        if (tid == 0) sh_eprev = 0.0f;
    }
    __syncthreads();
    if (tid < 64) {
        const float* sy_part = (const float*)t_acc;
        float s = 0.f;
#pragma unroll
        for (int c2 = 0; c2 < 16; ++c2) s += sy_part[tid * 17 + c2];
        sy_lds[tid] = s;
    }
    __syncthreads();

    // ---- gemm: kf = x . y^T (3-pass split bf16) ----
    f32x4 kf[4][4] = {};
    {
        const int rowbase = (w << 6) + l15;
        const int kofs = q * 8;
#pragma unroll 1
        for (int ks = 0; ks < 16; ++ks) {
            bf16x8 ah[4], al[4], bh[4], bl[4];
#pragma unroll
            for (int i = 0; i < 4; ++i) {
                const size_t xo = (size_t)(rowbase + i * 16) * 512 + ks * 32 + kofs;
                ah[i] = *(const bf16x8*)(xh + xo);
                al[i] = *(const bf16x8*)(xl + xo);
                const int cl = i * 16 + l15;
                const int bo = (cl * 1024 + ks * 64 + q * 16) ^ ((cl & 7) << 4);
                bh[i] = *(const bf16x8*)(ldsY + bo);
                bl[i] = *(const bf16x8*)(ldsY + 65536 + bo);
            }
#pragma unroll
            for (int i = 0; i < 4; ++i)
#pragma unroll
                for (int j = 0; j < 4; ++j) {
                    kf[i][j] = __builtin_amdgcn_mfma_f32_16x16x32_bf16(ah[i], bh[j], kf[i][j], 0, 0, 0);
                    kf[i][j] = __builtin_amdgcn_mfma_f32_16x16x32_bf16(ah[i], bl[j], kf[i][j], 0, 0, 0);
                    kf[i][j] = __builtin_amdgcn_mfma_f32_16x16x32_bf16(al[i], bh[j], kf[i][j], 0, 0, 0);
                }
        }
    }
    // ---- kf := M = sx + sy - 2*dot ----
#pragma unroll
    for (int i = 0; i < 4; ++i)
#pragma unroll
        for (int j = 0; j < 4; ++j) {
            const float syv = sy_lds[j * 16 + l15];
#pragma unroll
            for (int reg = 0; reg < 4; ++reg) {
                const int r = (w << 6) + i * 16 + (q << 2) + reg;
                kf[i][j][reg] = sx_lds[r] + syv - 2.0f * kf[i][j][reg];
            }
        }
    // ---- row-min: xor-reduce -> LDS redistribute -> scattered publish ----
    {
        float mn[4][4];
#pragma unroll
        for (int i = 0; i < 4; ++i)
#pragma unroll
            for (int reg = 0; reg < 4; ++reg) {
                float m = fminf(fminf(kf[i][0][reg], kf[i][1][reg]),
                                fminf(kf[i][2][reg], kf[i][3][reg]));
#pragma unroll
                for (int o = 1; o < 16; o <<= 1) m = fminf(m, __shfl_xor(m, o));
                mn[i][reg] = m;
            }
        if (l15 == 0) {
#pragma unroll
            for (int i = 0; i < 4; ++i)
#pragma unroll
                for (int reg = 0; reg < 4; ++reg)
                    srow_lds[w][i * 16 + (q << 2) + reg] = mn[i][reg];
        }
        __syncthreads();
        sysstoref(&spart2[(size_t)tid * 256 + b], srow_lds[w][lane]);
        __syncthreads();                         // vmcnt drain: publishes at L3
        if (tid == 0) sysstoreu(&arr[b], 1u);    // arrival
    }
    // leaders reduce min over 256 writers for their 64 rows; tagged publish
    if (b < 16) {
        if (tid < 256) { while (sysloadu(&arr[tid]) < 1u) __builtin_amdgcn_s_sleep(1); }
        __syncthreads();
        const int lrow = (b << 6) + (w << 2) + q;
        const float* sp = spart2 + (size_t)lrow * 256 + (l15 << 4);
        float m = sysloadf(&sp[0]);
#pragma unroll
        for (int k = 1; k < 16; ++k) m = fminf(m, sysloadf(&sp[k]));
        m = fminf(m, __shfl_xor(m, 1));
        m = fminf(m, __shfl_xor(m, 2));
        m = fminf(m, __shfl_xor(m, 4));
        m = fminf(m, __shfl_xor(m, 8));
        if (l15 == 0)
            sysstoreu64(&mmintag[lrow], (1ull << 32) | (u64)(unsigned)__float_as_uint(m));
    }
    // all blocks poll-read the tagged mins
    if (tid < 256) {
        const u64* ms = mmintag + (tid << 2);
#pragma unroll
        for (int k = 0; k < 4; ++k) {
            u64 e = sysloadu64(&ms[k]);
            while ((unsigned)(e >> 32) < 1u) { __builtin_amdgcn_s_sleep(1); e = sysloadu64(&ms[k]); }
            mmin_lds[(tid << 2) + k] = __uint_as_float((unsigned)e);
        }
    }
    __syncthreads();
    // ---- K = exp(-gamma*(M - Mmin)) in frags ----
#pragma unroll
    for (int i = 0; i < 4; ++i)
#pragma unroll
        for (int j = 0; j < 4; ++j)
#pragma unroll
            for (int reg = 0; reg < 4; ++reg) {
                const int r = (w << 6) + i * 16 + (q << 2) + reg;
                kf[i][j][reg] = __expf(-GAMMA_ * (kf[i][j][reg] - mmin_lds[r]));
            }

    // ---- Sinkhorn loop: one tagged leader exchange per iteration ----
    int cur = 0, vsel = 0;
    int it = 0;
    for (;; ++it) {
        const unsigned ep = (unsigned)it + 2u;
        // pass 1: row-partials of s over this block's 64 cols
        {
            float vv[4];
#pragma unroll
            for (int j = 0; j < 4; ++j) vv[j] = v_lds[cur][j * 16 + l15];
            float rs[4][4];
#pragma unroll
            for (int i = 0; i < 4; ++i)
#pragma unroll
                for (int reg = 0; reg < 4; ++reg) {
                    float pp = kf[i][0][reg] * vv[0];
                    pp = fmaf(kf[i][1][reg], vv[1], pp);
                    pp = fmaf(kf[i][2][reg], vv[2], pp);
                    pp = fmaf(kf[i][3][reg], vv[3], pp);
#pragma unroll
                    for (int o = 1; o < 16; o <<= 1) pp += __shfl_xor(pp, o);
                    rs[i][reg] = pp;
                }
            if (l15 == 0) {
#pragma unroll
                for (int i = 0; i < 4; ++i)
#pragma unroll
                    for (int reg = 0; reg < 4; ++reg)
                        srow_lds[w][i * 16 + (q << 2) + reg] = rs[i][reg];
            }
            __syncthreads();
            sysstoref(&spart2[(size_t)tid * 256 + b], srow_lds[w][lane]);
            if (tid == 0) sysstoref(&err_p[b], sh_eprev);
            __syncthreads();                        // vmcnt drain
            if (tid == 0) sysstoreu(&arr[b], ep);   // arrival
        }
        // leaders: reduce s for own 64 rows, compute u, tagged publish; lead0: err
        if (b < 16) {
            if (tid < 256) { while (sysloadu(&arr[tid]) < ep) __builtin_amdgcn_s_sleep(1); }
            __syncthreads();
            const int lrow = (b << 6) + (w << 2) + q;
            const float* sp = spart2 + (size_t)lrow * 256 + (l15 << 4);
            float s = 0.f;
#pragma unroll
            for (int k = 0; k < 16; ++k) s += sysloadf(&sp[k]);
            s += __shfl_xor(s, 1);
            s += __shfl_xor(s, 2);
            s += __shfl_xor(s, 4);
            s += __shfl_xor(s, 8);
            if (l15 == 0) {
                float un = u_prev * RVAL / fmaxf(u_prev * s, TINY_);  // speculative at break
                u_prev = un;
                sysstoreu64(&utag[((it & 1) << 10) + lrow],
                            ((u64)ep << 32) | (u64)(unsigned)__float_as_uint(un));
            }
            if (b == 0 && tid < 256) {
                float e = sysloadf(&err_p[tid]);
                e = waveRedSum(e);
                if (lane == 0)
                    sysstoreu64(&errtot[w], ((u64)ep << 32) | (u64)(unsigned)__float_as_uint(e));
            }
        }
        // all blocks: save prev u, poll-read fresh u + err
        if (tid < 256) {
#pragma unroll
            for (int k = 0; k < 4; ++k) u_prev_lds[(tid << 2) + k] = u_lds[(tid << 2) + k];
            const u64* us = utag + ((it & 1) << 10) + (tid << 2);
#pragma unroll
            for (int k = 0; k < 4; ++k) {
                u64 e = sysloadu64(&us[k]);
                while ((unsigned)(e >> 32) < ep) { __builtin_amdgcn_s_sleep(1); e = sysloadu64(&us[k]); }
                u_lds[(tid << 2) + k] = __uint_as_float((unsigned)e);
            }
        }
        if (tid == 0) {
            float et = 1e30f;
            if (it > 0) {
                et = 0.f;
#pragma unroll
                for (int k = 0; k < 4; ++k) {
                    u64 e = sysloadu64(&errtot[k]);
                    while ((unsigned)(e >> 32) < ep) { __builtin_amdgcn_s_sleep(1); e = sysloadu64(&errtot[k]); }
                    et += __uint_as_float((unsigned)e);
                }
            }
            sh_err = et;
        }
        __syncthreads();
        const float err = sh_err;
        const int brk = (err <= EPS_) ? 1 : ((it == 1000) ? 2 : 0);
        if (brk) { vsel = (brk == 1) ? (cur ^ 1) : cur; break; }
        // pass 2: t for own 64 cols; v update; err partial (published next iter)
        {
            float uu[4][4];
#pragma unroll
            for (int i = 0; i < 4; ++i)
#pragma unroll
                for (int reg = 0; reg < 4; ++reg)
                    uu[i][reg] = u_lds[(w << 6) + i * 16 + (q << 2) + reg];
            float tj[4];
#pragma unroll
            for (int j = 0; j < 4; ++j) {
                float t = 0.f;
#pragma unroll
                for (int i = 0; i < 4; ++i)
#pragma unroll
                    for (int reg = 0; reg < 4; ++reg)
                        t = fmaf(kf[i][j][reg], uu[i][reg], t);
                t += __shfl_xor(t, 16);
                t += __shfl_xor(t, 32);
                tj[j] = t;
            }
            if (q == 0) {
#pragma unroll
                for (int j = 0; j < 4; ++j) t_acc[w][j * 16 + l15] = tj[j];
            }
        }
        __syncthreads();
        if (tid < 64) {
            float t = 0.f;
#pragma unroll
            for (int w2 = 0; w2 < 16; ++w2) t += t_acc[w2][tid];
            float vc = v_lds[cur][tid];
            float beta = vc * t;
            float e = fabsf(beta - CVAL);
            v_lds[cur ^ 1][tid] = vc * CVAL / fmaxf(beta, TINY_);
            e = waveRedSum(e);
            if (tid == 0) sh_eprev = e;
        }
        __syncthreads();
        cur ^= 1;
    }

    __syncthreads();   // u_prev_lds coherent across threads before epilogue

    // ---- epilogue: P = u K v; loss = sum P*(Mmin - ln(K)/gamma) ----
    float vv[4];
#pragma unroll
    for (int j = 0; j < 4; ++j) vv[j] = v_lds[vsel][j * 16 + l15];
    float lsum = 0.f;
#pragma unroll
    for (int i = 0; i < 4; ++i)
#pragma unroll
        for (int reg = 0; reg < 4; ++reg) {
            const int r = (w << 6) + i * 16 + (q << 2) + reg;
            const float ur = u_prev_lds[r];
            const float mmr = mmin_lds[r];
            float* prow = Pbuf + (size_t)r * M_COLS + (b << 6) + l15;
#pragma unroll
            for (int j = 0; j < 4; ++j) {
                float kv = kf[i][j][reg];
                float pv = 0.f;
                if (kv > 0.f) {
                    pv = ur * kv * vv[j];
                    lsum = fmaf(pv, mmr - __logf(kv) * INV_GAMMA, lsum);
                }
                prow[j * 16] = pv;
            }
        }
    lsum = waveRedSum(lsum);
    if (lane == 0) red[w] = lsum;
    __syncthreads();
    if (tid == 0) {
        float s = 0.f;
#pragma unroll
        for (int i2 = 0; i2 < 16; ++i2) s += red[i2];
        atomicAdd(out, s);
    }
}

extern "C" void kernel_launch(void* const* d_in, const int* in_sizes, int n_in,
                              void* d_out, int out_size, void* d_ws, size_t ws_size,
                              hipStream_t stream) {
    const float* x = (const float*)d_in[0];
    const float* y = (const float*)d_in[1];
    float* out = (float*)d_out;
    char* wsb = (char*)d_ws;
    unsigned* arr   = (unsigned*)wsb;               // 256 u32   @ 0     (1 KB)
    u64* utag       = (u64*)(wsb + 1024);           // 2x1024 u64 (16 KB)
    u64* mmintag    = (u64*)(wsb + 17408);          // 1024 u64   (8 KB)
    u64* errtot     = (u64*)(wsb + 25600);          // 4 u64
    float* err_p    = (float*)(wsb + 25632);        // 256 f32    (1 KB)
    float* sx       = (float*)(wsb + 26656);        // 1024 f32   (4 KB)

    // scratch in the dead P-region of d_out (consumed before P write):
    unsigned short* xh = (unsigned short*)(out + 300000);    // 1024x512 bf16
    unsigned short* xl = (unsigned short*)(out + 600000);
    // spart2 at out + 10000000 (addressed inside the kernel)

    conv_x<<<N_ROWS, 64, 0, stream>>>(x, xh, xl, sx);
    init_state<<<16, 256, 0, stream>>>(arr, utag, mmintag, errtot, out);
    {
        const unsigned short *xhc = xh, *xlc = xl;
        const float *yc = y, *sxc = sx;
        void* args[] = {(void*)&xhc, (void*)&xlc, (void*)&yc, (void*)&sxc,
                        (void*)&out, (void*)&arr, (void*)&utag, (void*)&mmintag,
                        (void*)&errtot, (void*)&err_p};
        hipLaunchCooperativeKernel((const void*)sinkhorn_full, dim3(256), dim3(1024), args, 0, stream);
    }
}

// Round 11
// 242.663 us; speedup vs baseline: 1.3509x; 1.3509x over previous
//
#include <hip/hip_runtime.h>

#define N_ROWS 1024
#define M_COLS 16384
#define DIM 512

constexpr float GAMMA_ = 0.1f;
constexpr float INV_GAMMA = 10.0f;
constexpr float EPS_ = 0.005f;
constexpr float TINY_ = 1e-30f;
constexpr float RVAL = 1.0f / 1024.0f;
constexpr float CVAL = 1.0f / 16384.0f;

typedef __attribute__((ext_vector_type(8))) short bf16x8;
typedef __attribute__((ext_vector_type(4))) float f32x4;
typedef unsigned long long u64;

__device__ __forceinline__ float waveRedSum(float v) {
#pragma unroll
    for (int o = 32; o > 0; o >>= 1) v += __shfl_down(v, o);
    return v;
}

// ---- L2-bypassing (coherent-point) accesses: relaxed system-scope atomics ----
__device__ __forceinline__ unsigned sysloadu(const unsigned* p) {
    return __hip_atomic_load(p, __ATOMIC_RELAXED, __HIP_MEMORY_SCOPE_SYSTEM);
}
__device__ __forceinline__ void sysstoreu(unsigned* p, unsigned v) {
    __hip_atomic_store(p, v, __ATOMIC_RELAXED, __HIP_MEMORY_SCOPE_SYSTEM);
}
__device__ __forceinline__ float sysloadf(const float* p) {
    return __hip_atomic_load(p, __ATOMIC_RELAXED, __HIP_MEMORY_SCOPE_SYSTEM);
}
__device__ __forceinline__ void sysstoref(float* p, float v) {
    __hip_atomic_store(p, v, __ATOMIC_RELAXED, __HIP_MEMORY_SCOPE_SYSTEM);
}
__device__ __forceinline__ u64 sysloadu64(const u64* p) {
    return __hip_atomic_load(p, __ATOMIC_RELAXED, __HIP_MEMORY_SCOPE_SYSTEM);
}
__device__ __forceinline__ void sysstoreu64(u64* p, u64 v) {
    __hip_atomic_store(p, v, __ATOMIC_RELAXED, __HIP_MEMORY_SCOPE_SYSTEM);
}

// ---- fence-free barrier, R5 topology (block0 sweeps, broadcasts): ~0.95us ----
__device__ __forceinline__ void gbarx(unsigned* __restrict__ arr, unsigned* __restrict__ bcast,
                                      int b, int tid, unsigned e) {
    __syncthreads();                       // drains vmcnt: all waves' sys-stores acked at L3
    if (tid == 0) sysstoreu(&arr[b], e);
    if (b == 0) {
        if (tid < 256) {
            while (sysloadu(&arr[tid]) < e) __builtin_amdgcn_s_sleep(1);
        }
        __syncthreads();
        if (tid == 0) sysstoreu(bcast, e);
    } else {
        if (tid == 0) {
            while (sysloadu(bcast) < e) __builtin_amdgcn_s_sleep(1);
        }
    }
    __syncthreads();
}

// ---- bf16 split helper (RNE) ----
__device__ __forceinline__ unsigned bf16b(float f) {
    unsigned u = __float_as_uint(f);
    return (u + 0x7FFFu + ((u >> 16) & 1u)) >> 16;
}

// ---- conv_x: f32 -> bf16 hi/lo + row sqnorm; blocks 0..7 also init state ----
__global__ void conv_x(const float* __restrict__ X, unsigned short* __restrict__ xh,
                       unsigned short* __restrict__ xl, float* __restrict__ sx,
                       unsigned* __restrict__ arr, u64* __restrict__ tags,
                       float* __restrict__ out) {
    const int row = blockIdx.x, t = threadIdx.x;
    if (row < 8) {
        const int idx = row * 64 + t;     // 0..511
        arr[idx] = 0u;                    // arrival flags + bcast line
#pragma unroll
        for (int k = 0; k < 4; ++k) tags[idx * 4 + k] = 0ull;   // 2048 u64 tag region
        if (idx == 0) out[0] = 0.0f;
    }
    const float* xr = X + (size_t)row * DIM + t * 8;
    float4 a = *(const float4*)xr, c = *(const float4*)(xr + 4);
    float v[8] = {a.x, a.y, a.z, a.w, c.x, c.y, c.z, c.w};
    unsigned hs[8], ls[8];
    float sq = 0.f;
#pragma unroll
    for (int j = 0; j < 8; ++j) {
        unsigned h = bf16b(v[j]);
        hs[j] = h;
        ls[j] = bf16b(v[j] - __uint_as_float(h << 16));
        sq = fmaf(v[j], v[j], sq);
    }
    uint4 hv = make_uint4(hs[0] | (hs[1] << 16), hs[2] | (hs[3] << 16),
                          hs[4] | (hs[5] << 16), hs[6] | (hs[7] << 16));
    uint4 lv = make_uint4(ls[0] | (ls[1] << 16), ls[2] | (ls[3] << 16),
                          ls[4] | (ls[5] << 16), ls[6] | (ls[7] << 16));
    const size_t off = (size_t)row * 1024 + t * 16;   // bytes
    *(uint4*)((char*)xh + off) = hv;
    *(uint4*)((char*)xl + off) = lv;
    sq = waveRedSum(sq);
    if (t == 0) sx[row] = sq;
}

// ---- FUSED kernel. 256 blocks x 1024 thr. Block b owns cols [64b,64b+64) of
// K (register-resident MFMA C-fragments) AND rows [4b,4b+4) as u-owner.
// Per iteration: ONE gbarx (partials ready) + tagged owner publish:
//   wave1: reduce own 4 rows over 256 writers -> u (in-register u_prev) ->
//          store 4 floats + s_waitcnt + u64 tag {epoch | err-partial bits}.
//   wave5: poll all 256 tags (1 lane/line), fixed-order err reduce -> sh_err.
// WAR on spart2/tags serialized by the per-iter gbarx. Err is deferred one
// iteration (R9 semantics); break keeps v(t-2) [vsel=cur^1] and u(t-1)
// [ubuf parity p^1]; exhaustion keeps newest. Tags zeroed per launch.
__global__ __launch_bounds__(1024) void sinkhorn_full(
        const unsigned short* __restrict__ xh, const unsigned short* __restrict__ xl,
        const float* __restrict__ Y, const float* __restrict__ sx,
        float* __restrict__ ubuf, float* __restrict__ Mming,
        float* __restrict__ out, unsigned* __restrict__ arr, u64* __restrict__ tags) {
    const int tid = threadIdx.x;
    const int b = blockIdx.x;
    const int lane = tid & 63;
    const int w = tid >> 6;
    const int l15 = lane & 15;
    const int q = lane >> 4;
    float* Pbuf = out + 1;
    float* spart2 = out + 10000000;          // [256 writers][1056] f32 (dead P region)
    unsigned* bcast = arr + 288;

    __shared__ __align__(16) char ldsY[131072];   // hi 64KB | lo 64KB, swizzled
    __shared__ float sx_lds[1024];
    __shared__ float mmin_lds[1024];
    __shared__ float u_lds[1024];
    __shared__ float sy_lds[64];
    __shared__ float v_lds[2][64];
    __shared__ float t_acc[16][68];
    __shared__ float srow_lds[16][64];
    __shared__ float red[16];
    __shared__ float sh_err;
    __shared__ float sh_eprev;

    float u_prev = 1.0f;    // wave1: running u for this 16-lane group's owned row

    // ---- stage y tile: f32 -> split bf16 -> swizzled LDS; sy partials ----
    {
        const int row = tid >> 4;       // 0..63 (block's local col index)
        const int c = tid & 15;         // 32-f32 chunk within the row
        const float* yr = Y + (size_t)((b << 6) + row) * DIM + c * 32;
        const int swz = (row & 7) << 4;
        float sq = 0.f;
#pragma unroll
        for (int s2 = 0; s2 < 4; ++s2) {
            float4 f0 = *(const float4*)(yr + s2 * 8);
            float4 f1 = *(const float4*)(yr + s2 * 8 + 4);
            float v8[8] = {f0.x, f0.y, f0.z, f0.w, f1.x, f1.y, f1.z, f1.w};
            unsigned h[8], lo[8];
#pragma unroll
            for (int j = 0; j < 8; ++j) {
                h[j] = bf16b(v8[j]);
                lo[j] = bf16b(v8[j] - __uint_as_float(h[j] << 16));
                sq = fmaf(v8[j], v8[j], sq);
            }
            const int off = (row * 1024 + c * 64 + s2 * 16) ^ swz;
            *(uint4*)(ldsY + off) = make_uint4(h[0] | (h[1] << 16), h[2] | (h[3] << 16),
                                               h[4] | (h[5] << 16), h[6] | (h[7] << 16));
            *(uint4*)(ldsY + 65536 + off) = make_uint4(lo[0] | (lo[1] << 16), lo[2] | (lo[3] << 16),
                                                       lo[4] | (lo[5] << 16), lo[6] | (lo[7] << 16));
        }
        float* sy_part = (float*)t_acc;     // [64][17] fits t_acc
        sy_part[row * 17 + c] = sq;
        sx_lds[tid] = sx[tid];
        if (tid < 64) { v_lds[0][tid] = 1.0f; v_lds[1][tid] = 1.0f; }
        if (tid == 0) sh_eprev = 0.0f;
    }
    __syncthreads();
    if (tid < 64) {
        const float* sy_part = (const float*)t_acc;
        float s = 0.f;
#pragma unroll
        for (int c2 = 0; c2 < 16; ++c2) s += sy_part[tid * 17 + c2];
        sy_lds[tid] = s;
    }
    __syncthreads();

    // ---- gemm: kf = x . y^T (3-pass split bf16) ----
    f32x4 kf[4][4] = {};
    {
        const int rowbase = (w << 6) + l15;
        const int kofs = q * 8;
#pragma unroll 1
        for (int ks = 0; ks < 16; ++ks) {
            bf16x8 ah[4], al[4], bh[4], bl[4];
#pragma unroll
            for (int i = 0; i < 4; ++i) {
                const size_t xo = (size_t)(rowbase + i * 16) * 512 + ks * 32 + kofs;
                ah[i] = *(const bf16x8*)(xh + xo);
                al[i] = *(const bf16x8*)(xl + xo);
                const int cl = i * 16 + l15;
                const int bo = (cl * 1024 + ks * 64 + q * 16) ^ ((cl & 7) << 4);
                bh[i] = *(const bf16x8*)(ldsY + bo);
                bl[i] = *(const bf16x8*)(ldsY + 65536 + bo);
            }
#pragma unroll
            for (int i = 0; i < 4; ++i)
#pragma unroll
                for (int j = 0; j < 4; ++j) {
                    kf[i][j] = __builtin_amdgcn_mfma_f32_16x16x32_bf16(ah[i], bh[j], kf[i][j], 0, 0, 0);
                    kf[i][j] = __builtin_amdgcn_mfma_f32_16x16x32_bf16(ah[i], bl[j], kf[i][j], 0, 0, 0);
                    kf[i][j] = __builtin_amdgcn_mfma_f32_16x16x32_bf16(al[i], bh[j], kf[i][j], 0, 0, 0);
                }
        }
    }
    // ---- kf := M = sx + sy - 2*dot ----
#pragma unroll
    for (int i = 0; i < 4; ++i)
#pragma unroll
        for (int j = 0; j < 4; ++j) {
            const float syv = sy_lds[j * 16 + l15];
#pragma unroll
            for (int reg = 0; reg < 4; ++reg) {
                const int r = (w << 6) + i * 16 + (q << 2) + reg;
                kf[i][j][reg] = sx_lds[r] + syv - 2.0f * kf[i][j][reg];
            }
        }
    // ---- row-min exchange (epoch 1, tagged) ----
    {
        float mn[4][4];
#pragma unroll
        for (int i = 0; i < 4; ++i)
#pragma unroll
            for (int reg = 0; reg < 4; ++reg) {
                float m = fminf(fminf(kf[i][0][reg], kf[i][1][reg]),
                                fminf(kf[i][2][reg], kf[i][3][reg]));
#pragma unroll
                for (int o = 1; o < 16; o <<= 1) m = fminf(m, __shfl_xor(m, o));
                mn[i][reg] = m;
            }
        if (l15 == 0) {
#pragma unroll
            for (int i = 0; i < 4; ++i)
#pragma unroll
                for (int reg = 0; reg < 4; ++reg)
                    srow_lds[w][i * 16 + (q << 2) + reg] = mn[i][reg];
        }
        __syncthreads();
        sysstoref(&spart2[(size_t)b * 1056 + (w << 6) + lane], srow_lds[w][lane]);
    }
    gbarx(arr, bcast, b, tid, 1u);
    if (w == 1) {
        const int ll = lane & 15;
        const int r = (b << 2) + (lane >> 4);
        float m = sysloadf(&spart2[(size_t)ll * 1056 + r]);
#pragma unroll
        for (int k = 1; k < 16; ++k)
            m = fminf(m, sysloadf(&spart2[(size_t)(ll + 16 * k) * 1056 + r]));
        m = fminf(m, __shfl_xor(m, 1));
        m = fminf(m, __shfl_xor(m, 2));
        m = fminf(m, __shfl_xor(m, 4));
        m = fminf(m, __shfl_xor(m, 8));
        if (ll == 0) sysstoref(&Mming[r], m);
        asm volatile("s_waitcnt vmcnt(0)" ::: "memory");
        if (lane == 0) sysstoreu64(&tags[b * 8], (1ull << 32));
    } else if (w == 5) {
#pragma unroll
        for (int k = 0; k < 4; ++k) {
            const int ob = (lane << 2) + k;
            u64 t = sysloadu64(&tags[ob * 8]);
            while ((unsigned)(t >> 32) < 1u) { __builtin_amdgcn_s_sleep(1); t = sysloadu64(&tags[ob * 8]); }
        }
    }
    __syncthreads();
    if (tid < 256) {
#pragma unroll
        for (int k = 0; k < 4; ++k) mmin_lds[tid * 4 + k] = sysloadf(&Mming[tid * 4 + k]);
    }
    __syncthreads();
    // ---- K = exp(-gamma*(M - Mmin)) in frags ----
#pragma unroll
    for (int i = 0; i < 4; ++i)
#pragma unroll
        for (int j = 0; j < 4; ++j)
#pragma unroll
            for (int reg = 0; reg < 4; ++reg) {
                const int r = (w << 6) + i * 16 + (q << 2) + reg;
                kf[i][j][reg] = __expf(-GAMMA_ * (kf[i][j][reg] - mmin_lds[r]));
            }

    // ---- Sinkhorn loop: 1 gbarx + tagged owner publish per iteration ----
    int cur = 0, vsel = 0;
    int it = 0;
    for (;; ++it) {
        const unsigned ep = (unsigned)it + 2u;
        const int p = it & 1;
        // pass 1: row-partials of s over this block's 64 cols
        {
            float vv[4];
#pragma unroll
            for (int j = 0; j < 4; ++j) vv[j] = v_lds[cur][j * 16 + l15];
            float rs[4][4];
#pragma unroll
            for (int i = 0; i < 4; ++i)
#pragma unroll
                for (int reg = 0; reg < 4; ++reg) {
                    float pp = kf[i][0][reg] * vv[0];
                    pp = fmaf(kf[i][1][reg], vv[1], pp);
                    pp = fmaf(kf[i][2][reg], vv[2], pp);
                    pp = fmaf(kf[i][3][reg], vv[3], pp);
#pragma unroll
                    for (int o = 1; o < 16; o <<= 1) pp += __shfl_xor(pp, o);
                    rs[i][reg] = pp;
                }
            if (l15 == 0) {
#pragma unroll
                for (int i = 0; i < 4; ++i)
#pragma unroll
                    for (int reg = 0; reg < 4; ++reg)
                        srow_lds[w][i * 16 + (q << 2) + reg] = rs[i][reg];
            }
            __syncthreads();
            sysstoref(&spart2[(size_t)b * 1056 + (w << 6) + lane], srow_lds[w][lane]);
        }
        gbarx(arr, bcast, b, tid, ep);   // barrier A: all partials visible
        // window 1: wave1 = owner reduce + tagged publish; wave5 = poll + err
        if (w == 1) {
            const int ll = lane & 15;
            const int r = (b << 2) + (lane >> 4);
            float s = sysloadf(&spart2[(size_t)ll * 1056 + r]);
#pragma unroll
            for (int k = 1; k < 16; ++k)
                s += sysloadf(&spart2[(size_t)(ll + 16 * k) * 1056 + r]);
            s += __shfl_xor(s, 1);
            s += __shfl_xor(s, 2);
            s += __shfl_xor(s, 4);
            s += __shfl_xor(s, 8);
            float un = u_prev * RVAL / fmaxf(u_prev * s, TINY_);   // speculative at break
            u_prev = un;
            if (ll == 0) sysstoref(&ubuf[p * 1024 + r], un);
            asm volatile("s_waitcnt vmcnt(0)" ::: "memory");
            if (lane == 0)
                sysstoreu64(&tags[b * 8],
                            ((u64)ep << 32) | (u64)(unsigned)__float_as_uint(sh_eprev));
        } else if (w == 5) {
            float e4[4];
#pragma unroll
            for (int k = 0; k < 4; ++k) {
                const int ob = (lane << 2) + k;
                u64 t = sysloadu64(&tags[ob * 8]);
                while ((unsigned)(t >> 32) < ep) { __builtin_amdgcn_s_sleep(1); t = sysloadu64(&tags[ob * 8]); }
                e4[k] = __uint_as_float((unsigned)t);
            }
            float e = ((e4[0] + e4[1]) + e4[2]) + e4[3];   // fixed order: block-invariant
            e = waveRedSum(e);
            if (lane == 0) sh_err = (it > 0) ? e : 1e30f;
        }
        __syncthreads();
        const float err = sh_err;
        const int brk = (err <= EPS_) ? 1 : ((it == 1000) ? 2 : 0);
        if (brk) { vsel = (brk == 1) ? (cur ^ 1) : cur; break; }
        // u bulk read (tags confirmed -> all owner stores at coherent point)
        if (tid < 256) {
#pragma unroll
            for (int k = 0; k < 4; ++k) u_lds[tid * 4 + k] = sysloadf(&ubuf[p * 1024 + tid * 4 + k]);
        }
        __syncthreads();
        // pass 2: t for own 64 cols; v update; err partial (rides next iter's tag)
        {
            float uu[4][4];
#pragma unroll
            for (int i = 0; i < 4; ++i)
#pragma unroll
                for (int reg = 0; reg < 4; ++reg)
                    uu[i][reg] = u_lds[(w << 6) + i * 16 + (q << 2) + reg];
            float tj[4];
#pragma unroll
            for (int j = 0; j < 4; ++j) {
                float t = 0.f;
#pragma unroll
                for (int i = 0; i < 4; ++i)
#pragma unroll
                    for (int reg = 0; reg < 4; ++reg)
                        t = fmaf(kf[i][j][reg], uu[i][reg], t);
                t += __shfl_xor(t, 16);
                t += __shfl_xor(t, 32);
                tj[j] = t;
            }
            if (q == 0) {
#pragma unroll
                for (int j = 0; j < 4; ++j) t_acc[w][j * 16 + l15] = tj[j];
            }
        }
        __syncthreads();
        if (tid < 64) {
            float t = 0.f;
#pragma unroll
            for (int w2 = 0; w2 < 16; ++w2) t += t_acc[w2][tid];
            float vc = v_lds[cur][tid];
            float beta = vc * t;
            float e = fabsf(beta - CVAL);
            v_lds[cur ^ 1][tid] = vc * CVAL / fmaxf(beta, TINY_);
            e = waveRedSum(e);
            if (tid == 0) sh_eprev = e;
        }
        __syncthreads();
        cur ^= 1;
    }

    // ---- epilogue: P = u K v; loss = sum P*(Mmin - ln(K)/gamma) ----
    // u(t-1) = ubuf parity (it&1)^1 (tagged & drained at iter it-1).
    if (tid < 256) {
        const float* uEpi = ubuf + (((it & 1) ^ 1) << 10);
#pragma unroll
        for (int k = 0; k < 4; ++k) u_lds[tid * 4 + k] = sysloadf(&uEpi[tid * 4 + k]);
    }
    __syncthreads();
    float vv[4];
#pragma unroll
    for (int j = 0; j < 4; ++j) vv[j] = v_lds[vsel][j * 16 + l15];
    float lsum = 0.f;
#pragma unroll
    for (int i = 0; i < 4; ++i)
#pragma unroll
        for (int reg = 0; reg < 4; ++reg) {
            const int r = (w << 6) + i * 16 + (q << 2) + reg;
            const float ur = u_lds[r];
            const float mmr = mmin_lds[r];
            float* prow = Pbuf + (size_t)r * M_COLS + (b << 6) + l15;
#pragma unroll
            for (int j = 0; j < 4; ++j) {
                float kv = kf[i][j][reg];
                float pv = 0.f;
                if (kv > 0.f) {
                    pv = ur * kv * vv[j];
                    lsum = fmaf(pv, mmr - __logf(kv) * INV_GAMMA, lsum);
                }
                prow[j * 16] = pv;
            }
        }
    lsum = waveRedSum(lsum);
    if (lane == 0) red[w] = lsum;
    __syncthreads();
    if (tid == 0) {
        float s = 0.f;
#pragma unroll
        for (int i2 = 0; i2 < 16; ++i2) s += red[i2];
        atomicAdd(out, s);
    }
}

extern "C" void kernel_launch(void* const* d_in, const int* in_sizes, int n_in,
                              void* d_out, int out_size, void* d_ws, size_t ws_size,
                              hipStream_t stream) {
    const float* x = (const float*)d_in[0];
    const float* y = (const float*)d_in[1];
    float* out = (float*)d_out;
    char* wsb = (char*)d_ws;
    unsigned* arr = (unsigned*)wsb;             // 512 u32 (flags + bcast line) @ 0
    u64* tags     = (u64*)(wsb + 2048);         // 2048 u64 (256 tags, 64B stride) 16KB
    float* ubuf   = (float*)(wsb + 18432);      // 2 x 1024 f32
    float* Mming  = (float*)(wsb + 26624);      // 1024 f32
    float* sx     = (float*)(wsb + 30720);      // 1024 f32

    // scratch in the dead P-region of d_out (consumed before P write):
    unsigned short* xh = (unsigned short*)(out + 300000);    // 1024x512 bf16
    unsigned short* xl = (unsigned short*)(out + 600000);
    // spart2 at out + 10000000 (addressed inside the kernel)

    conv_x<<<N_ROWS, 64, 0, stream>>>(x, xh, xl, sx, arr, tags, out);
    {
        const unsigned short *xhc = xh, *xlc = xl;
        const float *yc = y, *sxc = sx;
        void* args[] = {(void*)&xhc, (void*)&xlc, (void*)&yc, (void*)&sxc,
                        (void*)&ubuf, (void*)&Mming, (void*)&out, (void*)&arr, (void*)&tags};
        hipLaunchCooperativeKernel((const void*)sinkhorn_full, dim3(256), dim3(1024), args, 0, stream);
    }
}

// Round 12
// 208.070 us; speedup vs baseline: 1.5754x; 1.1663x over previous
//
#include <hip/hip_runtime.h>

#define N_ROWS 1024
#define M_COLS 16384
#define DIM 512

constexpr float GAMMA_ = 0.1f;
constexpr float INV_GAMMA = 10.0f;
constexpr float EPS_ = 0.005f;
constexpr float TINY_ = 1e-30f;
constexpr float RVAL = 1.0f / 1024.0f;
constexpr float CVAL = 1.0f / 16384.0f;

typedef __attribute__((ext_vector_type(8))) short bf16x8;
typedef __attribute__((ext_vector_type(4))) float f32x4;

__device__ __forceinline__ float waveRedSum(float v) {
#pragma unroll
    for (int o = 32; o > 0; o >>= 1) v += __shfl_down(v, o);
    return v;
}
__device__ __forceinline__ float waveRedMin(float v) {
#pragma unroll
    for (int o = 32; o > 0; o >>= 1) v = fminf(v, __shfl_down(v, o));
    return v;
}

// ---- L2-bypassing (coherent-point) accesses: relaxed system-scope atomics ----
__device__ __forceinline__ unsigned sysloadu(const unsigned* p) {
    return __hip_atomic_load(p, __ATOMIC_RELAXED, __HIP_MEMORY_SCOPE_SYSTEM);
}
__device__ __forceinline__ void sysstoreu(unsigned* p, unsigned v) {
    __hip_atomic_store(p, v, __ATOMIC_RELAXED, __HIP_MEMORY_SCOPE_SYSTEM);
}
__device__ __forceinline__ float sysloadf(const float* p) {
    return __hip_atomic_load(p, __ATOMIC_RELAXED, __HIP_MEMORY_SCOPE_SYSTEM);
}
__device__ __forceinline__ void sysstoref(float* p, float v) {
    __hip_atomic_store(p, v, __ATOMIC_RELAXED, __HIP_MEMORY_SCOPE_SYSTEM);
}

// ---- fence-free barrier, R5 topology (block0 sweeps, broadcasts): ~0.95us ----
__device__ __forceinline__ void gbarx(unsigned* __restrict__ arr, unsigned* __restrict__ bcast,
                                      int b, int tid, unsigned e) {
    __syncthreads();                       // drains vmcnt: all waves' sys-stores acked at L3
    if (tid == 0) sysstoreu(&arr[b], e);
    if (b == 0) {
        if (tid < 256) {
            while (sysloadu(&arr[tid]) < e) __builtin_amdgcn_s_sleep(1);
        }
        __syncthreads();
        if (tid == 0) sysstoreu(bcast, e);
    } else {
        if (tid == 0) {
            while (sysloadu(bcast) < e) __builtin_amdgcn_s_sleep(1);
        }
    }
    __syncthreads();
}

// ---- bf16 split helper (RNE) ----
__device__ __forceinline__ unsigned bf16b(float f) {
    unsigned u = __float_as_uint(f);
    return (u + 0x7FFFu + ((u >> 16) & 1u)) >> 16;
}

// ---- conv_x: f32 -> bf16 hi/lo (linear layout) + row sqnorm. 1024 blk x 64 thr ----
__global__ void conv_x(const float* __restrict__ X, unsigned short* __restrict__ xh,
                       unsigned short* __restrict__ xl, float* __restrict__ sx) {
    const int row = blockIdx.x, t = threadIdx.x;
    const float* xr = X + (size_t)row * DIM + t * 8;
    float4 a = *(const float4*)xr, c = *(const float4*)(xr + 4);
    float v[8] = {a.x, a.y, a.z, a.w, c.x, c.y, c.z, c.w};
    unsigned hs[8], ls[8];
    float sq = 0.f;
#pragma unroll
    for (int j = 0; j < 8; ++j) {
        unsigned h = bf16b(v[j]);
        hs[j] = h;
        ls[j] = bf16b(v[j] - __uint_as_float(h << 16));
        sq = fmaf(v[j], v[j], sq);
    }
    uint4 hv = make_uint4(hs[0] | (hs[1] << 16), hs[2] | (hs[3] << 16),
                          hs[4] | (hs[5] << 16), hs[6] | (hs[7] << 16));
    uint4 lv = make_uint4(ls[0] | (ls[1] << 16), ls[2] | (ls[3] << 16),
                          ls[4] | (ls[5] << 16), ls[6] | (ls[7] << 16));
    const size_t off = (size_t)row * 1024 + t * 16;   // bytes
    *(uint4*)((char*)xh + off) = hv;
    *(uint4*)((char*)xl + off) = lv;
    sq = waveRedSum(sq);
    if (t == 0) sx[row] = sq;
}

// ---- per-launch state init (graph replays do NOT re-poison ws/out) ----
__global__ void init_state(float* __restrict__ ubuf, unsigned* __restrict__ flags,
                           float* __restrict__ out) {
    int idx = blockIdx.x * blockDim.x + threadIdx.x;
    if (idx < 512) flags[idx] = 0u;
    if (idx < 512) { ubuf[idx * 4] = 1.0f; ubuf[idx * 4 + 1] = 1.0f;
                     ubuf[idx * 4 + 2] = 1.0f; ubuf[idx * 4 + 3] = 1.0f; }
    if (idx == 0) out[0] = 0.0f;
}

// ---- FUSED: y-tile f32->split-bf16 staging + MFMA gemm (K in C-fragments) +
// row-min exchange + K=exp + Sinkhorn (2 gbarx/iter) + P/loss epilogue.
// 256 blocks x 1024 thr. Block b owns cols [64b,64b+64), wave w rows [64w,64w+64).
// kf[i][j][reg]: row = 64w+16i+4q+reg (q=lane>>4), col(local) = 16j+l15.
// spart2 layout: [writer b][1056] (rows 0..1023 + err slot 1024), publish is one
// coalesced 256B sc-store per wave via LDS redistribute.
__global__ __launch_bounds__(1024, 4) void sinkhorn_full(
        const unsigned short* __restrict__ xh, const unsigned short* __restrict__ xl,
        const float* __restrict__ Y, const float* __restrict__ sx,
        float* __restrict__ ubuf, float* __restrict__ Mming,
        float* __restrict__ out, unsigned* __restrict__ flags) {
    const int tid = threadIdx.x;
    const int b = blockIdx.x;
    const int lane = tid & 63;
    const int w = tid >> 6;
    const int l15 = lane & 15;
    const int q = lane >> 4;
    float* Pbuf = out + 1;
    float* spart2 = out + 10000000;          // [256][1056] f32 (dead P region)
    unsigned* arr = flags;                   // [256]
    unsigned* bcast = flags + 288;           // separate line

    __shared__ __align__(16) char ldsY[131072];   // hi 64KB | lo 64KB, swizzled
    __shared__ float sx_lds[1024];
    __shared__ float mmin_lds[1024];
    __shared__ float u_lds[1024];
    __shared__ float sy_lds[64];
    __shared__ float v_lds[2][64];
    __shared__ float t_acc[16][68];
    __shared__ float srow_lds[16][64];
    __shared__ float red[16];
    __shared__ float sh_err;
    __shared__ float sh_eprev;

    // ---- stage y tile: f32 -> split bf16 -> swizzled LDS; sy partials ----
    {
        const int row = tid >> 4;       // 0..63 (block's local col index)
        const int c = tid & 15;         // 32 f32 chunk within the row
        const float* yr = Y + (size_t)((b << 6) + row) * DIM + c * 32;
        const int swz = (row & 7) << 4;
        float sq = 0.f;
#pragma unroll
        for (int s2 = 0; s2 < 4; ++s2) {
            float4 f0 = *(const float4*)(yr + s2 * 8);
            float4 f1 = *(const float4*)(yr + s2 * 8 + 4);
            float v8[8] = {f0.x, f0.y, f0.z, f0.w, f1.x, f1.y, f1.z, f1.w};
            unsigned h[8], lo[8];
#pragma unroll
            for (int j = 0; j < 8; ++j) {
                h[j] = bf16b(v8[j]);
                lo[j] = bf16b(v8[j] - __uint_as_float(h[j] << 16));
                sq = fmaf(v8[j], v8[j], sq);
            }
            const int off = (row * 1024 + c * 64 + s2 * 16) ^ swz;
            *(uint4*)(ldsY + off) = make_uint4(h[0] | (h[1] << 16), h[2] | (h[3] << 16),
                                               h[4] | (h[5] << 16), h[6] | (h[7] << 16));
            *(uint4*)(ldsY + 65536 + off) = make_uint4(lo[0] | (lo[1] << 16), lo[2] | (lo[3] << 16),
                                                       lo[4] | (lo[5] << 16), lo[6] | (lo[7] << 16));
        }
        float* sy_part = (float*)t_acc;     // [64][17] = 1088 floats, fits t_acc exactly
        sy_part[row * 17 + c] = sq;
        sx_lds[tid] = sx[tid];
        if (tid < 64) { v_lds[0][tid] = 1.0f; v_lds[1][tid] = 1.0f; }
        if (tid == 0) sh_eprev = 0.0f;
    }
    __syncthreads();
    if (tid < 64) {
        const float* sy_part = (const float*)t_acc;
        float s = 0.f;
#pragma unroll
        for (int c2 = 0; c2 < 16; ++c2) s += sy_part[tid * 17 + c2];
        sy_lds[tid] = s;
    }
    __syncthreads();

    // ---- gemm: kf = x . y^T (3-pass split bf16) ----
    f32x4 kf[4][4] = {};
    {
        const int rowbase = (w << 6) + l15;
        const int kofs = q * 8;
#pragma unroll 1
        for (int ks = 0; ks < 16; ++ks) {
            bf16x8 ah[4], al[4], bh[4], bl[4];
#pragma unroll
            for (int i = 0; i < 4; ++i) {
                const size_t xo = (size_t)(rowbase + i * 16) * 512 + ks * 32 + kofs;
                ah[i] = *(const bf16x8*)(xh + xo);
                al[i] = *(const bf16x8*)(xl + xo);
                const int cl = i * 16 + l15;
                const int bo = (cl * 1024 + ks * 64 + q * 16) ^ ((cl & 7) << 4);
                bh[i] = *(const bf16x8*)(ldsY + bo);
                bl[i] = *(const bf16x8*)(ldsY + 65536 + bo);
            }
#pragma unroll
            for (int i = 0; i < 4; ++i)
#pragma unroll
                for (int j = 0; j < 4; ++j) {
                    kf[i][j] = __builtin_amdgcn_mfma_f32_16x16x32_bf16(ah[i], bh[j], kf[i][j], 0, 0, 0);
                    kf[i][j] = __builtin_amdgcn_mfma_f32_16x16x32_bf16(ah[i], bl[j], kf[i][j], 0, 0, 0);
                    kf[i][j] = __builtin_amdgcn_mfma_f32_16x16x32_bf16(al[i], bh[j], kf[i][j], 0, 0, 0);
                }
        }
    }
    // ---- kf := M = sx + sy - 2*dot ----
#pragma unroll
    for (int i = 0; i < 4; ++i)
#pragma unroll
        for (int j = 0; j < 4; ++j) {
            const float syv = sy_lds[j * 16 + l15];
#pragma unroll
            for (int reg = 0; reg < 4; ++reg) {
                const int r = (w << 6) + i * 16 + (q << 2) + reg;
                kf[i][j][reg] = sx_lds[r] + syv - 2.0f * kf[i][j][reg];
            }
        }
    // ---- row-min partials: xor-reduce (all lanes valid) -> LDS redistribute ->
    // one coalesced 256B publish per wave ----
    {
        float mn[4][4];
#pragma unroll
        for (int i = 0; i < 4; ++i)
#pragma unroll
            for (int reg = 0; reg < 4; ++reg) {
                float m = fminf(fminf(kf[i][0][reg], kf[i][1][reg]),
                                fminf(kf[i][2][reg], kf[i][3][reg]));
#pragma unroll
                for (int o = 1; o < 16; o <<= 1) m = fminf(m, __shfl_xor(m, o));
                mn[i][reg] = m;
            }
        if (l15 == 0) {
#pragma unroll
            for (int i = 0; i < 4; ++i)
#pragma unroll
                for (int reg = 0; reg < 4; ++reg)
                    srow_lds[w][i * 16 + (q << 2) + reg] = mn[i][reg];
        }
        __syncthreads();
        sysstoref(&spart2[(size_t)b * 1056 + (w << 6) + lane], srow_lds[w][lane]);
    }
    gbarx(arr, bcast, b, tid, 1u);
    // owner block b reduces rows 4b..4b+3 over 256 writers (waves 1..4)
    if (w >= 1 && w <= 4) {
        const int r = (b << 2) + (w - 1);
        float m = fminf(fminf(sysloadf(&spart2[(size_t)lane * 1056 + r]),
                              sysloadf(&spart2[(size_t)(lane + 64) * 1056 + r])),
                        fminf(sysloadf(&spart2[(size_t)(lane + 128) * 1056 + r]),
                              sysloadf(&spart2[(size_t)(lane + 192) * 1056 + r])));
        m = waveRedMin(m);
        if (lane == 0) sysstoref(&Mming[r], m);
    }
    gbarx(arr, bcast, b, tid, 2u);
    if (tid < 256) {
#pragma unroll
        for (int k2 = 0; k2 < 4; ++k2) mmin_lds[tid * 4 + k2] = sysloadf(&Mming[tid * 4 + k2]);
    }
    __syncthreads();
    // ---- K = exp(-gamma*(M - Mmin)) in frags ----
#pragma unroll
    for (int i = 0; i < 4; ++i)
#pragma unroll
        for (int j = 0; j < 4; ++j)
#pragma unroll
            for (int reg = 0; reg < 4; ++reg) {
                const int r = (w << 6) + i * 16 + (q << 2) + reg;
                kf[i][j][reg] = __expf(-GAMMA_ * (kf[i][j][reg] - mmin_lds[r]));
            }

    // ---- Sinkhorn loop (2 gbarx/iter; coalesced publish) ----
    int cur = 0, vsel = 0, brk = 0;
    int it = 0;
    for (;; ++it) {
        const unsigned ep = 3u + 2u * (unsigned)it;
        // pass 1: row-partials of s over this block's 64 cols
        {
            float vv[4];
#pragma unroll
            for (int j = 0; j < 4; ++j) vv[j] = v_lds[cur][j * 16 + l15];
            float rs[4][4];
#pragma unroll
            for (int i = 0; i < 4; ++i)
#pragma unroll
                for (int reg = 0; reg < 4; ++reg) {
                    float pp = kf[i][0][reg] * vv[0];
                    pp = fmaf(kf[i][1][reg], vv[1], pp);
                    pp = fmaf(kf[i][2][reg], vv[2], pp);
                    pp = fmaf(kf[i][3][reg], vv[3], pp);
#pragma unroll
                    for (int o = 1; o < 16; o <<= 1) pp += __shfl_xor(pp, o);
                    rs[i][reg] = pp;
                }
            if (l15 == 0) {
#pragma unroll
                for (int i = 0; i < 4; ++i)
#pragma unroll
                    for (int reg = 0; reg < 4; ++reg)
                        srow_lds[w][i * 16 + (q << 2) + reg] = rs[i][reg];
            }
            __syncthreads();
            sysstoref(&spart2[(size_t)b * 1056 + (w << 6) + lane], srow_lds[w][lane]);
            if (tid == 0) sysstoref(&spart2[(size_t)b * 1056 + 1024], sh_eprev);
        }
        gbarx(arr, bcast, b, tid, ep);   // barrier A: spart + prev errpart visible
        float* uOld = ubuf + (((it & 1) ^ 1) << 10);
        float* uNew = ubuf + ((it & 1) << 10);
        {
            if (w == 0) {
                float e = 0.f;
                if (it > 0)
                    e = sysloadf(&spart2[(size_t)lane * 1056 + 1024]) +
                        sysloadf(&spart2[(size_t)(lane + 64) * 1056 + 1024]) +
                        sysloadf(&spart2[(size_t)(lane + 128) * 1056 + 1024]) +
                        sysloadf(&spart2[(size_t)(lane + 192) * 1056 + 1024]);
                e = waveRedSum(e);
                if (lane == 0) sh_err = (it > 0) ? e : 1e30f;
            } else if (w <= 4) {
                const int r = (b << 2) + (w - 1);
                float s = sysloadf(&spart2[(size_t)lane * 1056 + r]) +
                          sysloadf(&spart2[(size_t)(lane + 64) * 1056 + r]) +
                          sysloadf(&spart2[(size_t)(lane + 128) * 1056 + r]) +
                          sysloadf(&spart2[(size_t)(lane + 192) * 1056 + r]);
                s = waveRedSum(s);
                if (lane == 0) {
                    float uo = sysloadf(&uOld[r]);
                    sysstoref(&uNew[r], uo * RVAL / fmaxf(uo * s, TINY_));  // speculative at break
                }
            }
        }
        __syncthreads();
        float err = sh_err;
        brk = (err <= EPS_) ? 1 : ((it == 1000) ? 2 : 0);
        gbarx(arr, bcast, b, tid, ep + 1u);  // barrier B: u visible / epilogue-safety
        if (brk) { vsel = (brk == 1) ? (cur ^ 1) : cur; break; }
        if (tid < 256) {
#pragma unroll
            for (int k2 = 0; k2 < 4; ++k2) u_lds[tid * 4 + k2] = sysloadf(&uNew[tid * 4 + k2]);
        }
        __syncthreads();
        // pass 2: t for own 64 cols; v update; err partial (published next iter)
        {
            float uu[4][4];
#pragma unroll
            for (int i = 0; i < 4; ++i)
#pragma unroll
                for (int reg = 0; reg < 4; ++reg)
                    uu[i][reg] = u_lds[(w << 6) + i * 16 + (q << 2) + reg];
            float tj[4];
#pragma unroll
            for (int j = 0; j < 4; ++j) {
                float t = 0.f;
#pragma unroll
                for (int i = 0; i < 4; ++i)
#pragma unroll
                    for (int reg = 0; reg < 4; ++reg)
                        t = fmaf(kf[i][j][reg], uu[i][reg], t);
                t += __shfl_xor(t, 16);
                t += __shfl_xor(t, 32);
                tj[j] = t;
            }
            if (q == 0) {
#pragma unroll
                for (int j = 0; j < 4; ++j) t_acc[w][j * 16 + l15] = tj[j];
            }
        }
        __syncthreads();
        if (tid < 64) {
            float t = 0.f;
#pragma unroll
            for (int w2 = 0; w2 < 16; ++w2) t += t_acc[w2][tid];
            float vc = v_lds[cur][tid];
            float beta = vc * t;
            float e = fabsf(beta - CVAL);
            v_lds[cur ^ 1][tid] = vc * CVAL / fmaxf(beta, TINY_);
            e = waveRedSum(e);
            if (tid == 0) sh_eprev = e;
        }
        __syncthreads();
        cur ^= 1;
    }

    // ---- epilogue: P = u K v; loss = sum P*(Mmin - ln(K)/gamma) ----
    const float* uEpi = ubuf + (((it & 1) ^ 1) << 10);
    if (tid < 256) {
#pragma unroll
        for (int k2 = 0; k2 < 4; ++k2) u_lds[tid * 4 + k2] = sysloadf(&uEpi[tid * 4 + k2]);
    }
    __syncthreads();
    float vv[4];
#pragma unroll
    for (int j = 0; j < 4; ++j) vv[j] = v_lds[vsel][j * 16 + l15];
    float lsum = 0.f;
#pragma unroll
    for (int i = 0; i < 4; ++i)
#pragma unroll
        for (int reg = 0; reg < 4; ++reg) {
            const int r = (w << 6) + i * 16 + (q << 2) + reg;
            const float ur = u_lds[r];
            const float mmr = mmin_lds[r];
            float* prow = Pbuf + (size_t)r * M_COLS + (b << 6) + l15;
#pragma unroll
            for (int j = 0; j < 4; ++j) {
                float kv = kf[i][j][reg];
                float pv = 0.f;
                if (kv > 0.f) {
                    pv = ur * kv * vv[j];
                    lsum = fmaf(pv, mmr - __logf(kv) * INV_GAMMA, lsum);
                }
                prow[j * 16] = pv;
            }
        }
    lsum = waveRedSum(lsum);
    if (lane == 0) red[w] = lsum;
    __syncthreads();
    if (tid == 0) {
        float s = 0.f;
#pragma unroll
        for (int i2 = 0; i2 < 16; ++i2) s += red[i2];
        atomicAdd(out, s);
    }
}

extern "C" void kernel_launch(void* const* d_in, const int* in_sizes, int n_in,
                              void* d_out, int out_size, void* d_ws, size_t ws_size,
                              hipStream_t stream) {
    const float* x = (const float*)d_in[0];
    const float* y = (const float*)d_in[1];
    float* out = (float*)d_out;
    float* ws = (float*)d_ws;
    float* sx    = ws;                           // 1024
    float* Mming = ws + 1024;                    // 1024
    float* ubuf  = ws + 2048;                    // 2 x 1024
    unsigned* flags = (unsigned*)(ws + 4096);    // 512 uints

    // scratch in the dead P-region of d_out (all consumed before P write):
    unsigned short* xh = (unsigned short*)(out + 300000);    // 1024x512 bf16
    unsigned short* xl = (unsigned short*)(out + 600000);
    // spart2 at out + 10000000 (addressed inside the kernel)

    conv_x<<<N_ROWS, 64, 0, stream>>>(x, xh, xl, sx);
    init_state<<<2, 256, 0, stream>>>(ubuf, flags, out);
    {
        const unsigned short *xhc = xh, *xlc = xl;
        const float *yc = y, *sxc = sx;
        void* args[] = {(void*)&xhc, (void*)&xlc, (void*)&yc, (void*)&sxc,
                        (void*)&ubuf, (void*)&Mming, (void*)&out, (void*)&flags};
        hipLaunchCooperativeKernel((const void*)sinkhorn_full, dim3(256), dim3(1024), args, 0, stream);
    }
}